// Round 6
// baseline (6765.955 us; speedup 1.0000x reference)
//
#include <hip/hip_runtime.h>
#include <hip/hip_bf16.h>
#include <cstdint>
#include <cstddef>

#define HID 512
#define N_INT 131072
#define N_INIT 32768

typedef __attribute__((ext_vector_type(8))) short short8_t;
typedef __attribute__((ext_vector_type(4))) float floatx4;

__device__ __forceinline__ float bf2f(unsigned short u) {
  return __uint_as_float(((unsigned)u) << 16);
}
__device__ __forceinline__ unsigned short f2bf_rne(float x) {
  unsigned u = __float_as_uint(x);
  unsigned r = u + 0x7FFF + ((u >> 16) & 1);
  return (unsigned short)(r >> 16);
}
__device__ __forceinline__ void st_split(unsigned short* hi, unsigned short* lo,
                                         size_t off, float x) {
  unsigned short h = f2bf_rne(x);
  hi[off] = h;
  lo[off] = f2bf_rne(x - bf2f(h));
}

// fraglet offset for element (row, col) in a [rows][512] matrix stored as
// MFMA-operand fraglets: fraglet (row>>4, col>>5); lane = ((col>>3)&3)*16
// + (row&15); elem = col&7.  One fraglet = 1KB contiguous.
__device__ __forceinline__ size_t foff(int row, int col) {
  return (size_t)(row >> 4) * 8192 + (size_t)(col >> 5) * 512 +
         (size_t)(((col >> 3) & 3) * 128) + (size_t)((row & 15) << 3) +
         (size_t)(col & 7);
}

// ---------------------------------------------------------------------------
// Layer 0 (2 -> 512), closed-form tangents; writes bf16 hi/lo fraglet planes.
// ---------------------------------------------------------------------------
__global__ __launch_bounds__(512) void layer0_int(
    const float* __restrict__ xt, long row0, int rows,
    const float* __restrict__ W0, const float* __restrict__ b0,
    unsigned short* __restrict__ act, size_t P)
{
  long i = blockIdx.x;
  if (i >= rows) return;
  int j = threadIdx.x;
  float x = xt[(row0 + i) * 2 + 0];
  float t = xt[(row0 + i) * 2 + 1];
  float wx = W0[j];
  float wt = W0[HID + j];
  float a = fmaf(x, wx, fmaf(t, wt, b0[j]));
  float y = tanhf(a);
  float d = 1.f - y * y;
  size_t o = foff((int)i, j);
  st_split(act + 0 * P, act + 1 * P, o, y);
  st_split(act + 2 * P, act + 3 * P, o, d * wt);
  st_split(act + 4 * P, act + 5 * P, o, -2.f * y * d * wt * wt);
  st_split(act + 6 * P, act + 7 * P, o, d * wx);
  st_split(act + 8 * P, act + 9 * P, o, -2.f * y * d * wx * wx);
}

__global__ __launch_bounds__(512) void layer0_init(
    const float* __restrict__ xt, long row0, int rows,
    const float* __restrict__ W0, const float* __restrict__ b0,
    unsigned short* __restrict__ act, size_t P)
{
  long i = blockIdx.x;
  if (i >= rows) return;
  int j = threadIdx.x;
  float x = xt[(row0 + i) * 2 + 0];
  float t = xt[(row0 + i) * 2 + 1];
  float wx = W0[j];
  float wt = W0[HID + j];
  float a = fmaf(x, wx, fmaf(t, wt, b0[j]));
  float y = tanhf(a);
  float d = 1.f - y * y;
  size_t o = foff((int)i, j);
  st_split(act + 0 * P, act + 1 * P, o, y);
  st_split(act + 2 * P, act + 3 * P, o, d * wt);
}

// ---------------------------------------------------------------------------
// W split + pack into B-fraglet layout (n -> fraglet row role):
//   fraglet (n>>4, k>>5); lane = ((k>>3)&3)*16 + (n&15); elem = k&7.
// ---------------------------------------------------------------------------
__global__ __launch_bounds__(512) void wsplit(
    const float* __restrict__ W,
    unsigned short* __restrict__ WfH, unsigned short* __restrict__ WfL)
{
  int n = blockIdx.x;
  int k = threadIdx.x;
  float w = W[(size_t)k * HID + n];
  size_t o = ((((size_t)(n >> 4) * 16 + (k >> 5)) * 64
               + ((k >> 3) & 3) * 16 + (n & 15)) << 3) + (k & 7);
  st_split(WfH, WfL, o, w);
}

// ---------------------------------------------------------------------------
// Fused NS-stream split-bf16 MFMA GEMM, NO LDS, NO BARRIERS.
// 256 thr = 4 waves (2m x 2n); block tile 32x128; wave tile 16x64 per stream.
// A and B both read as MFMA fraglets via coalesced 16B/lane loads (L2-hot:
// XCD-grouped swizzle keeps writer and reader of a panel on the same XCD).
// C = Ah@Wh + Ah@Wl + Al@Wh (fp32 accum) per stream, W shared across streams.
// LAST=false: epilogue writes next layer's A in fraglet hi/lo bf16 planes.
// LAST=true : epilogue writes the 2 loss-relevant streams as f32 row-major.
// ---------------------------------------------------------------------------
template <int NS, bool LAST>
__global__ __launch_bounds__(256, 2) void gemm_mfma(
    const unsigned short* __restrict__ inp,   // 2*NS fraglet planes of P elems
    const unsigned short* __restrict__ WfH,   // fraglet-packed 512x512
    const unsigned short* __restrict__ WfL,
    const float* __restrict__ bias,
    unsigned short* __restrict__ outp,        // 2*NS fraglet planes (!LAST)
    float* __restrict__ outf,                 // 2 f32 planes (LAST)
    size_t P, int nwg)
{
  const int bid = blockIdx.x;
  // XCD-grouped order (nwg multiple of 8): the 4 n-blocks of an m-panel are
  // consecutive logical ids -> same XCD across dispatches -> A panel in L2.
  const int o = (bid & 7) * (nwg >> 3) + (bid >> 3);
  const long bm = (long)(o >> 2) << 5;
  const int bn = (o & 3) << 7;

  const int lane = threadIdx.x & 63;
  const int wv = threadIdx.x >> 6;   // 0..3
  const int wm = wv >> 1;            // 16-row half
  const int wn = wv & 1;             // 64-col half

  floatx4 acc[NS][4];
#pragma unroll
  for (int s = 0; s < NS; ++s)
#pragma unroll
    for (int cf = 0; cf < 4; ++cf)
#pragma unroll
      for (int e = 0; e < 4; ++e) acc[s][cf][e] = 0.f;

  const int mt = (int)(bm >> 4) + wm;  // this wave's m_tile
  const unsigned short* abase = inp + (size_t)mt * 8192 + (lane << 3);
  const int bnt = (bn >> 4) + wn * 4;  // first of this wave's 4 n_tiles
  const unsigned short* bbh = WfH + ((size_t)bnt << 13) + (lane << 3);
  const unsigned short* bbl = WfL + ((size_t)bnt << 13) + (lane << 3);

#pragma unroll
  for (int t = 0; t < 16; ++t) {
    short8_t bh[4], bl[4], ah[NS], al[NS];
#pragma unroll
    for (int cf = 0; cf < 4; ++cf) {
      bh[cf] = *(const short8_t*)(bbh + ((size_t)cf << 13) + (t << 9));
      bl[cf] = *(const short8_t*)(bbl + ((size_t)cf << 13) + (t << 9));
    }
#pragma unroll
    for (int s = 0; s < NS; ++s) {
      ah[s] = *(const short8_t*)(abase + (size_t)(2 * s) * P + (t << 9));
      al[s] = *(const short8_t*)(abase + (size_t)(2 * s + 1) * P + (t << 9));
    }
#pragma unroll
    for (int s = 0; s < NS; ++s)
#pragma unroll
      for (int cf = 0; cf < 4; ++cf) {
        acc[s][cf] = __builtin_amdgcn_mfma_f32_16x16x32_bf16(ah[s], bh[cf], acc[s][cf], 0, 0, 0);
        acc[s][cf] = __builtin_amdgcn_mfma_f32_16x16x32_bf16(ah[s], bl[cf], acc[s][cf], 0, 0, 0);
        acc[s][cf] = __builtin_amdgcn_mfma_f32_16x16x32_bf16(al[s], bh[cf], acc[s][cf], 0, 0, 0);
      }
    asm volatile("" ::: "memory");  // bound scheduler lookahead per k-step
  }

  // ---- epilogue: tanh coupling
  const int frow = lane & 15;
  const int fq = lane >> 4;
#pragma unroll
  for (int cf = 0; cf < 4; ++cf) {
    const int col = bn + wn * 64 + cf * 16 + frow;
    const float bv = bias[col];
    const size_t fbase = (size_t)mt * 8192 + (size_t)(col >> 5) * 512 +
                         (size_t)(((col >> 3) & 3) * 128) + (size_t)(col & 7);
#pragma unroll
    for (int j = 0; j < 4; ++j) {
      const float a0 = acc[0][cf][j] + bv;
      const float e = __expf(2.f * a0);
      const float y = 1.f - __fdividef(2.f, e + 1.f);
      const float d = 1.f - y * y;
      const float a1 = acc[1][cf][j];
      const float o1 = d * a1;
      if (LAST) {
        const size_t row = (size_t)(bm + wm * 16 + fq * 4 + j);
        const size_t off = (row << 9) + col;
        if (NS == 5) {
          const float a2 = acc[2][cf][j];
          const float a3 = acc[3][cf][j];
          const float a4 = acc[4][cf][j];
          const float o2 = fmaf(-2.f * y * a1, o1, d * a2);
          const float o3 = d * a3;
          const float o4 = fmaf(-2.f * y * a3, o3, d * a4);
          outf[off] = o2;        // u_tt'' activation
          outf[P + off] = o4;    // u_xx'' activation
        } else {
          outf[off] = y;         // h activation
          outf[P + off] = o1;    // u_t' activation
        }
      } else {
        const size_t off = fbase + (size_t)((fq * 4 + j) << 3);
        st_split(outp + 0 * P, outp + 1 * P, off, y);
        st_split(outp + 2 * P, outp + 3 * P, off, o1);
        if (NS == 5) {
          const float a2 = acc[2][cf][j];
          const float a3 = acc[3][cf][j];
          const float a4 = acc[4][cf][j];
          const float o2 = fmaf(-2.f * y * a1, o1, d * a2);
          const float o3 = d * a3;
          const float o4 = fmaf(-2.f * y * a3, o3, d * a4);
          st_split(outp + 4 * P, outp + 5 * P, off, o2);
          st_split(outp + 6 * P, outp + 7 * P, off, o3);
          st_split(outp + 8 * P, outp + 9 * P, off, o4);
        }
      }
    }
  }
}

// ---------------------------------------------------------------------------
// Final layer (512 -> 1) dots + loss accumulation, f32 row-major inputs.
// ---------------------------------------------------------------------------
__global__ __launch_bounds__(256) void final_int(
    const float* __restrict__ uf, size_t P,
    const float* __restrict__ W4, const float* __restrict__ f,
    const float* __restrict__ c, float* __restrict__ out,
    int rows, float scale)
{
  __shared__ float ls[4];
  int lane = threadIdx.x & 63, w = threadIdx.x >> 6;
  long i = (long)blockIdx.x * 4 + w;
  float val = 0.f;
  if (i < rows) {
    const float* ut = uf + (i << 9) + (lane << 3);
    const float* ux = ut + P;
    float s_t = 0.f, s_x = 0.f;
#pragma unroll
    for (int j = 0; j < 8; ++j) {
      float wv4 = W4[(lane << 3) + j];
      s_t = fmaf(ut[j], wv4, s_t);
      s_x = fmaf(ux[j], wv4, s_x);
    }
#pragma unroll
    for (int off = 32; off; off >>= 1) {
      s_t += __shfl_xor(s_t, off);
      s_x += __shfl_xor(s_x, off);
    }
    if (lane == 0) {
      float c0 = c[0];
      float pred = s_t - c0 * c0 * s_x;
      float r = pred - f[i];
      val = r * r;
    }
  }
  if (lane == 0) ls[w] = val;
  __syncthreads();
  if (threadIdx.x == 0)
    atomicAdd(out + 2, scale * (ls[0] + ls[1] + ls[2] + ls[3]));
}

__global__ __launch_bounds__(256) void final_init(
    const float* __restrict__ uf, size_t P,
    const float* __restrict__ W4, const float* __restrict__ b4,
    const float* __restrict__ g, const float* __restrict__ gd,
    float* __restrict__ out, int rows, float scale)
{
  __shared__ float ls0[4], ls1[4];
  int lane = threadIdx.x & 63, w = threadIdx.x >> 6;
  long i = (long)blockIdx.x * 4 + w;
  float v0 = 0.f, v1 = 0.f;
  if (i < rows) {
    const float* h = uf + (i << 9) + (lane << 3);
    const float* tt = h + P;
    float su = 0.f, stt = 0.f;
#pragma unroll
    for (int j = 0; j < 8; ++j) {
      float wv4 = W4[(lane << 3) + j];
      su = fmaf(h[j], wv4, su);
      stt = fmaf(tt[j], wv4, stt);
    }
#pragma unroll
    for (int off = 32; off; off >>= 1) {
      su += __shfl_xor(su, off);
      stt += __shfl_xor(stt, off);
    }
    if (lane == 0) {
      float r0 = su + b4[0] - g[i];
      float r1 = stt - gd[i];
      v0 = r0 * r0;
      v1 = r1 * r1;
    }
  }
  if (lane == 0) { ls0[w] = v0; ls1[w] = v1; }
  __syncthreads();
  if (threadIdx.x == 0) {
    atomicAdd(out + 0, scale * (ls0[0] + ls0[1] + ls0[2] + ls0[3]));
    atomicAdd(out + 1, scale * (ls1[0] + ls1[1] + ls1[2] + ls1[3]));
  }
}

// ---------------------------------------------------------------------------
extern "C" void kernel_launch(void* const* d_in, const int* in_sizes, int n_in,
                              void* d_out, int out_size, void* d_ws, size_t ws_size,
                              hipStream_t stream)
{
  const float* xt_int  = (const float*)d_in[0];
  const float* f       = (const float*)d_in[1];
  const float* xt_init = (const float*)d_in[2];
  const float* g       = (const float*)d_in[3];
  const float* gd      = (const float*)d_in[4];
  const float* W0 = (const float*)d_in[5];
  const float* b0 = (const float*)d_in[6];
  const float* W1 = (const float*)d_in[7];
  const float* b1 = (const float*)d_in[8];
  const float* W2 = (const float*)d_in[9];
  const float* b2 = (const float*)d_in[10];
  const float* W3 = (const float*)d_in[11];
  const float* b3 = (const float*)d_in[12];
  const float* W4 = (const float*)d_in[13];
  const float* b4 = (const float*)d_in[14];
  const float* c  = (const float*)d_in[15];
  float* out = (float*)d_out;

  hipMemsetAsync(out, 0, 3 * sizeof(float), stream);

  unsigned short* wsp = (unsigned short*)d_ws;
  const size_t WT1 = (size_t)HID * HID;     // one 512x512 plane (elems)
  const size_t wtotal = 6 * WT1;            // 3 layers x {hi,lo}
  unsigned short* Wt = wsp;

  // per-row cost: 2 bf16 buffers x 10 planes x 512 + 1 f32 buffer x 2 planes
  const size_t row_bytes = 2 * 10 * HID * 2 + 2 * HID * 4;  // 24576
  long maxRc = (long)((ws_size - wtotal * 2) / row_bytes);
  long Rc = 128;
  while (Rc * 2 <= maxRc && Rc < 8192) Rc <<= 1;
  size_t P = (size_t)Rc * HID;
  unsigned short* bufA = wsp + wtotal;
  unsigned short* bufB = bufA + 10 * P;
  float* fbuf = (float*)(bufB + 10 * P);

  wsplit<<<HID, HID, 0, stream>>>(W1, Wt + 0 * WT1, Wt + 1 * WT1);
  wsplit<<<HID, HID, 0, stream>>>(W2, Wt + 2 * WT1, Wt + 3 * WT1);
  wsplit<<<HID, HID, 0, stream>>>(W3, Wt + 4 * WT1, Wt + 5 * WT1);

  const float sc_f = 0.5f / (float)N_INT;
  const float sc_i = 0.5f / (float)N_INIT;

  // ---- interior pass (5 streams) ----
  for (long i0 = 0; i0 < N_INT; i0 += Rc) {
    long rem = N_INT - i0;
    int rows = (int)(rem < Rc ? rem : Rc);
    layer0_int<<<rows, HID, 0, stream>>>(xt_int, i0, rows, W0, b0, bufA, P);
    int nwg = (rows / 32) * 4;
    gemm_mfma<5, false><<<nwg, 256, 0, stream>>>(bufA, Wt + 0 * WT1, Wt + 1 * WT1, b1, bufB, nullptr, P, nwg);
    gemm_mfma<5, false><<<nwg, 256, 0, stream>>>(bufB, Wt + 2 * WT1, Wt + 3 * WT1, b2, bufA, nullptr, P, nwg);
    gemm_mfma<5, true><<<nwg, 256, 0, stream>>>(bufA, Wt + 4 * WT1, Wt + 5 * WT1, b3, nullptr, fbuf, P, nwg);
    final_int<<<(rows + 3) / 4, 256, 0, stream>>>(fbuf, P, W4, f + i0, c, out, rows, sc_f);
  }

  // ---- init pass (2 streams) ----
  for (long i0 = 0; i0 < N_INIT; i0 += Rc) {
    long rem = N_INIT - i0;
    int rows = (int)(rem < Rc ? rem : Rc);
    layer0_init<<<rows, HID, 0, stream>>>(xt_init, i0, rows, W0, b0, bufA, P);
    int nwg = (rows / 32) * 4;
    gemm_mfma<2, false><<<nwg, 256, 0, stream>>>(bufA, Wt + 0 * WT1, Wt + 1 * WT1, b1, bufB, nullptr, P, nwg);
    gemm_mfma<2, false><<<nwg, 256, 0, stream>>>(bufB, Wt + 2 * WT1, Wt + 3 * WT1, b2, bufA, nullptr, P, nwg);
    gemm_mfma<2, true><<<nwg, 256, 0, stream>>>(bufA, Wt + 4 * WT1, Wt + 5 * WT1, b3, nullptr, fbuf, P, nwg);
    final_init<<<(rows + 3) / 4, 256, 0, stream>>>(fbuf, P, W4, b4, g + i0, gd + i0, out, rows, sc_i);
  }
}

// Round 7
// 5239.121 us; speedup vs baseline: 1.2914x; 1.2914x over previous
//
#include <hip/hip_runtime.h>
#include <hip/hip_bf16.h>
#include <cstdint>
#include <cstddef>

#define HID 512
#define N_INT 131072
#define N_INIT 32768

typedef __attribute__((ext_vector_type(8))) short short8_t;
typedef __attribute__((ext_vector_type(4))) float floatx4;

__device__ __forceinline__ float bf2f(unsigned short u) {
  return __uint_as_float(((unsigned)u) << 16);
}
__device__ __forceinline__ unsigned short f2bf_rne(float x) {
  unsigned u = __float_as_uint(x);
  unsigned r = u + 0x7FFF + ((u >> 16) & 1);
  return (unsigned short)(r >> 16);
}
__device__ __forceinline__ void st_split(unsigned short* hi, unsigned short* lo,
                                         size_t off, float x) {
  unsigned short h = f2bf_rne(x);
  hi[off] = h;
  lo[off] = f2bf_rne(x - bf2f(h));
}
__device__ __forceinline__ void gl_lds16(const unsigned short* g, unsigned short* l) {
  __builtin_amdgcn_global_load_lds(
      (const __attribute__((address_space(1))) unsigned int*)g,
      (__attribute__((address_space(3))) unsigned int*)l, 16, 0, 0);
}

// fraglet offset for element (row, col) in a [rows][512] matrix stored as
// MFMA-operand fraglets: fraglet (row>>4, col>>5); lane = ((col>>3)&3)*16
// + (row&15); elem = col&7.  One fraglet = 1KB contiguous.
__device__ __forceinline__ size_t foff(int row, int col) {
  return (size_t)(row >> 4) * 8192 + (size_t)(col >> 5) * 512 +
         (size_t)(((col >> 3) & 3) * 128) + (size_t)((row & 15) << 3) +
         (size_t)(col & 7);
}

// ---------------------------------------------------------------------------
// Layer 0 (2 -> 512), closed-form tangents; writes bf16 hi/lo fraglet planes.
// ---------------------------------------------------------------------------
__global__ __launch_bounds__(512) void layer0_int(
    const float* __restrict__ xt, long row0, int rows,
    const float* __restrict__ W0, const float* __restrict__ b0,
    unsigned short* __restrict__ act, size_t P)
{
  long i = blockIdx.x;
  if (i >= rows) return;
  int j = threadIdx.x;
  float x = xt[(row0 + i) * 2 + 0];
  float t = xt[(row0 + i) * 2 + 1];
  float wx = W0[j];
  float wt = W0[HID + j];
  float a = fmaf(x, wx, fmaf(t, wt, b0[j]));
  float y = tanhf(a);
  float d = 1.f - y * y;
  size_t o = foff((int)i, j);
  st_split(act + 0 * P, act + 1 * P, o, y);
  st_split(act + 2 * P, act + 3 * P, o, d * wt);
  st_split(act + 4 * P, act + 5 * P, o, -2.f * y * d * wt * wt);
  st_split(act + 6 * P, act + 7 * P, o, d * wx);
  st_split(act + 8 * P, act + 9 * P, o, -2.f * y * d * wx * wx);
}

__global__ __launch_bounds__(512) void layer0_init(
    const float* __restrict__ xt, long row0, int rows,
    const float* __restrict__ W0, const float* __restrict__ b0,
    unsigned short* __restrict__ act, size_t P)
{
  long i = blockIdx.x;
  if (i >= rows) return;
  int j = threadIdx.x;
  float x = xt[(row0 + i) * 2 + 0];
  float t = xt[(row0 + i) * 2 + 1];
  float wx = W0[j];
  float wt = W0[HID + j];
  float a = fmaf(x, wx, fmaf(t, wt, b0[j]));
  float y = tanhf(a);
  float d = 1.f - y * y;
  size_t o = foff((int)i, j);
  st_split(act + 0 * P, act + 1 * P, o, y);
  st_split(act + 2 * P, act + 3 * P, o, d * wt);
}

// ---------------------------------------------------------------------------
// W split + pack into B-fraglet layout (n -> fraglet row role):
//   fraglet (n>>4, k>>5); lane = ((k>>3)&3)*16 + (n&15); elem = k&7.
// ---------------------------------------------------------------------------
__global__ __launch_bounds__(512) void wsplit(
    const float* __restrict__ W,
    unsigned short* __restrict__ WfH, unsigned short* __restrict__ WfL)
{
  int n = blockIdx.x;
  int k = threadIdx.x;
  float w = W[(size_t)k * HID + n];
  size_t o = ((((size_t)(n >> 4) * 16 + (k >> 5)) * 64
               + ((k >> 3) & 3) * 16 + (n & 15)) << 3) + (k & 7);
  st_split(WfH, WfL, o, w);
}

// ---------------------------------------------------------------------------
// Fused NS-stream split-bf16 MFMA GEMM.
// 256 thr = 4 waves (1m x 4n); block tile 32x128; wave tile 32x32 per stream.
// A: staged to LDS as fraglets (global_load_lds, linear both sides), double-
//    buffered; shared by all 4 waves (kills the TCP-port duplication).
// B: register-double-buffered fraglet loads from L2 (1 wave per n-tile pair).
// Pipeline: stage(t+1)+B(t+1) issued at loop top; 60-MFMA burst covers the
// latency; raw s_barrier + explicit vmcnt(0) (no __syncthreads full drain).
// C = Ah@Wh + Ah@Wl + Al@Wh (fp32 accum) per stream, W shared across streams.
// ---------------------------------------------------------------------------
template <int NS, bool LAST>
__global__ __launch_bounds__(256, 2) void gemm_mfma(
    const unsigned short* __restrict__ inp,   // 2*NS fraglet planes of P elems
    const unsigned short* __restrict__ WfH,   // fraglet-packed 512x512
    const unsigned short* __restrict__ WfL,
    const float* __restrict__ bias,
    unsigned short* __restrict__ outp,        // 2*NS fraglet planes (!LAST)
    float* __restrict__ outf,                 // 2 f32 planes (LAST)
    size_t P, int nwg)
{
  __shared__ unsigned short Asm[2][NS * 4 * 512];  // per k-step: NS*4 fraglets

  const int bid = blockIdx.x;
  // XCD-grouped order (nwg multiple of 8): the 4 n-blocks of an m-panel are
  // consecutive logical ids -> same XCD -> A panel re-reads hit that L2/L3.
  const int o = (bid & 7) * (nwg >> 3) + (bid >> 3);
  const long bm = (long)(o >> 2) << 5;
  const int bn = (o & 3) << 7;

  const int lane = threadIdx.x & 63;
  const int wv = threadIdx.x >> 6;   // 0..3 = n-quarter

  floatx4 acc[NS][2][2];             // [stream][rf(m16)][cf(n16)]
#pragma unroll
  for (int s = 0; s < NS; ++s)
#pragma unroll
    for (int rf = 0; rf < 2; ++rf)
#pragma unroll
      for (int cf = 0; cf < 2; ++cf)
#pragma unroll
        for (int e = 0; e < 4; ++e) acc[s][rf][cf][e] = 0.f;

  const int mt0 = (int)(bm >> 4);

  // ---- A staging: NS*4 fraglets per k-step, NS per wave.
  // fraglet id f = s*4 + mt*2 + p  (mt: m-tile within block, p: hi/lo)
  const unsigned short* asrc[NS];
  unsigned adst[NS];
#pragma unroll
  for (int u = 0; u < NS; ++u) {
    const int f = wv * NS + u;
    const int s = f >> 2, mtl = (f >> 1) & 1, p = f & 1;
    asrc[u] = inp + (size_t)(2 * s + p) * P + (size_t)(mt0 + mtl) * 8192 + (lane << 3);
    adst[u] = (unsigned)f * 512;
  }

  // ---- B fraglet pointers (16B/lane coalesced); this wave's 2 n-tiles
  const int bnt = (bn >> 4) + wv * 2;
  const unsigned short* bbh = WfH + ((size_t)bnt << 13) + (lane << 3);
  const unsigned short* bbl = WfL + ((size_t)bnt << 13) + (lane << 3);

  short8_t bh[2][2], bl[2][2];  // [k-parity][cf]

  // ---- prologue: stage A(0), load B(0)
#pragma unroll
  for (int u = 0; u < NS; ++u)
    gl_lds16(asrc[u], &Asm[0][adst[u]]);
#pragma unroll
  for (int cf = 0; cf < 2; ++cf) {
    bh[0][cf] = *(const short8_t*)(bbh + ((size_t)cf << 13));
    bl[0][cf] = *(const short8_t*)(bbl + ((size_t)cf << 13));
  }
  asm volatile("s_waitcnt vmcnt(0)" ::: "memory");
  __builtin_amdgcn_s_barrier();

#pragma unroll
  for (int t = 0; t < 16; ++t) {
    const int cur = t & 1;
    if (t < 15) {
      // issue next tile's A staging + B register prefetch (in flight during MFMA)
#pragma unroll
      for (int u = 0; u < NS; ++u)
        gl_lds16(asrc[u] + ((t + 1) << 9), &Asm[cur ^ 1][adst[u]]);
#pragma unroll
      for (int cf = 0; cf < 2; ++cf) {
        bh[cur ^ 1][cf] = *(const short8_t*)(bbh + ((size_t)cf << 13) + ((t + 1) << 9));
        bl[cur ^ 1][cf] = *(const short8_t*)(bbl + ((size_t)cf << 13) + ((t + 1) << 9));
      }
      asm volatile("" ::: "memory");  // keep prefetch issue ahead of compute
    }
    // compute k-tile t: A frags from LDS (linear, conflict-free), B from regs
#pragma unroll
    for (int s = 0; s < NS; ++s) {
      const unsigned short* As = &Asm[cur][(unsigned)s * 2048 + (lane << 3)];
      const short8_t ah0 = *(const short8_t*)(As);
      const short8_t al0 = *(const short8_t*)(As + 512);
      const short8_t ah1 = *(const short8_t*)(As + 1024);
      const short8_t al1 = *(const short8_t*)(As + 1536);
#pragma unroll
      for (int cf = 0; cf < 2; ++cf) {
        acc[s][0][cf] = __builtin_amdgcn_mfma_f32_16x16x32_bf16(ah0, bh[cur][cf], acc[s][0][cf], 0, 0, 0);
        acc[s][0][cf] = __builtin_amdgcn_mfma_f32_16x16x32_bf16(ah0, bl[cur][cf], acc[s][0][cf], 0, 0, 0);
        acc[s][0][cf] = __builtin_amdgcn_mfma_f32_16x16x32_bf16(al0, bh[cur][cf], acc[s][0][cf], 0, 0, 0);
        acc[s][1][cf] = __builtin_amdgcn_mfma_f32_16x16x32_bf16(ah1, bh[cur][cf], acc[s][1][cf], 0, 0, 0);
        acc[s][1][cf] = __builtin_amdgcn_mfma_f32_16x16x32_bf16(ah1, bl[cur][cf], acc[s][1][cf], 0, 0, 0);
        acc[s][1][cf] = __builtin_amdgcn_mfma_f32_16x16x32_bf16(al1, bh[cur][cf], acc[s][1][cf], 0, 0, 0);
      }
    }
    if (t < 15) {
      asm volatile("s_waitcnt vmcnt(0)" ::: "memory");  // A(t+1)+B(t+1) landed
      __builtin_amdgcn_s_barrier();
    }
  }

  // ---- epilogue: tanh coupling
  const int frow = lane & 15;
  const int fq = lane >> 4;
#pragma unroll
  for (int rf = 0; rf < 2; ++rf) {
#pragma unroll
    for (int cf = 0; cf < 2; ++cf) {
      const int col = bn + wv * 32 + cf * 16 + frow;
      const float bv = bias[col];
      const size_t fbase = (size_t)(mt0 + rf) * 8192 + (size_t)(col >> 5) * 512 +
                           (size_t)(((col >> 3) & 3) * 128) + (size_t)(col & 7);
#pragma unroll
      for (int j = 0; j < 4; ++j) {
        const float a0 = acc[0][rf][cf][j] + bv;
        const float e = __expf(2.f * a0);
        const float y = 1.f - __fdividef(2.f, e + 1.f);
        const float d = 1.f - y * y;
        const float a1 = acc[1][rf][cf][j];
        const float o1 = d * a1;
        if (LAST) {
          const size_t row = (size_t)(bm + rf * 16 + fq * 4 + j);
          const size_t off = (row << 9) + col;
          if (NS == 5) {
            const float a2 = acc[2][rf][cf][j];
            const float a3 = acc[3][rf][cf][j];
            const float a4 = acc[4][rf][cf][j];
            const float o2 = fmaf(-2.f * y * a1, o1, d * a2);
            const float o3 = d * a3;
            const float o4 = fmaf(-2.f * y * a3, o3, d * a4);
            outf[off] = o2;        // u_tt'' activation
            outf[P + off] = o4;    // u_xx'' activation
          } else {
            outf[off] = y;         // h activation
            outf[P + off] = o1;    // u_t' activation
          }
        } else {
          const size_t off = fbase + (size_t)((fq * 4 + j) << 3);
          st_split(outp + 0 * P, outp + 1 * P, off, y);
          st_split(outp + 2 * P, outp + 3 * P, off, o1);
          if (NS == 5) {
            const float a2 = acc[2][rf][cf][j];
            const float a3 = acc[3][rf][cf][j];
            const float a4 = acc[4][rf][cf][j];
            const float o2 = fmaf(-2.f * y * a1, o1, d * a2);
            const float o3 = d * a3;
            const float o4 = fmaf(-2.f * y * a3, o3, d * a4);
            st_split(outp + 4 * P, outp + 5 * P, off, o2);
            st_split(outp + 6 * P, outp + 7 * P, off, o3);
            st_split(outp + 8 * P, outp + 9 * P, off, o4);
          }
        }
      }
    }
  }
}

// ---------------------------------------------------------------------------
// Final layer (512 -> 1) dots + loss accumulation, f32 row-major inputs.
// ---------------------------------------------------------------------------
__global__ __launch_bounds__(256) void final_int(
    const float* __restrict__ uf, size_t P,
    const float* __restrict__ W4, const float* __restrict__ f,
    const float* __restrict__ c, float* __restrict__ out,
    int rows, float scale)
{
  __shared__ float ls[4];
  int lane = threadIdx.x & 63, w = threadIdx.x >> 6;
  long i = (long)blockIdx.x * 4 + w;
  float val = 0.f;
  if (i < rows) {
    const float* ut = uf + (i << 9) + (lane << 3);
    const float* ux = ut + P;
    float s_t = 0.f, s_x = 0.f;
#pragma unroll
    for (int j = 0; j < 8; ++j) {
      float wv4 = W4[(lane << 3) + j];
      s_t = fmaf(ut[j], wv4, s_t);
      s_x = fmaf(ux[j], wv4, s_x);
    }
#pragma unroll
    for (int off = 32; off; off >>= 1) {
      s_t += __shfl_xor(s_t, off);
      s_x += __shfl_xor(s_x, off);
    }
    if (lane == 0) {
      float c0 = c[0];
      float pred = s_t - c0 * c0 * s_x;
      float r = pred - f[i];
      val = r * r;
    }
  }
  if (lane == 0) ls[w] = val;
  __syncthreads();
  if (threadIdx.x == 0)
    atomicAdd(out + 2, scale * (ls[0] + ls[1] + ls[2] + ls[3]));
}

__global__ __launch_bounds__(256) void final_init(
    const float* __restrict__ uf, size_t P,
    const float* __restrict__ W4, const float* __restrict__ b4,
    const float* __restrict__ g, const float* __restrict__ gd,
    float* __restrict__ out, int rows, float scale)
{
  __shared__ float ls0[4], ls1[4];
  int lane = threadIdx.x & 63, w = threadIdx.x >> 6;
  long i = (long)blockIdx.x * 4 + w;
  float v0 = 0.f, v1 = 0.f;
  if (i < rows) {
    const float* h = uf + (i << 9) + (lane << 3);
    const float* tt = h + P;
    float su = 0.f, stt = 0.f;
#pragma unroll
    for (int j = 0; j < 8; ++j) {
      float wv4 = W4[(lane << 3) + j];
      su = fmaf(h[j], wv4, su);
      stt = fmaf(tt[j], wv4, stt);
    }
#pragma unroll
    for (int off = 32; off; off >>= 1) {
      su += __shfl_xor(su, off);
      stt += __shfl_xor(stt, off);
    }
    if (lane == 0) {
      float r0 = su + b4[0] - g[i];
      float r1 = stt - gd[i];
      v0 = r0 * r0;
      v1 = r1 * r1;
    }
  }
  if (lane == 0) { ls0[w] = v0; ls1[w] = v1; }
  __syncthreads();
  if (threadIdx.x == 0) {
    atomicAdd(out + 0, scale * (ls0[0] + ls0[1] + ls0[2] + ls0[3]));
    atomicAdd(out + 1, scale * (ls1[0] + ls1[1] + ls1[2] + ls1[3]));
  }
}

// ---------------------------------------------------------------------------
extern "C" void kernel_launch(void* const* d_in, const int* in_sizes, int n_in,
                              void* d_out, int out_size, void* d_ws, size_t ws_size,
                              hipStream_t stream)
{
  const float* xt_int  = (const float*)d_in[0];
  const float* f       = (const float*)d_in[1];
  const float* xt_init = (const float*)d_in[2];
  const float* g       = (const float*)d_in[3];
  const float* gd      = (const float*)d_in[4];
  const float* W0 = (const float*)d_in[5];
  const float* b0 = (const float*)d_in[6];
  const float* W1 = (const float*)d_in[7];
  const float* b1 = (const float*)d_in[8];
  const float* W2 = (const float*)d_in[9];
  const float* b2 = (const float*)d_in[10];
  const float* W3 = (const float*)d_in[11];
  const float* b3 = (const float*)d_in[12];
  const float* W4 = (const float*)d_in[13];
  const float* b4 = (const float*)d_in[14];
  const float* c  = (const float*)d_in[15];
  float* out = (float*)d_out;

  hipMemsetAsync(out, 0, 3 * sizeof(float), stream);

  unsigned short* wsp = (unsigned short*)d_ws;
  const size_t WT1 = (size_t)HID * HID;     // one 512x512 plane (elems)
  const size_t wtotal = 6 * WT1;            // 3 layers x {hi,lo}
  unsigned short* Wt = wsp;

  // per-row cost: 2 bf16 buffers x 10 planes x 512 + 1 f32 buffer x 2 planes
  const size_t row_bytes = 2 * 10 * HID * 2 + 2 * HID * 4;  // 24576
  long maxRc = (long)((ws_size - wtotal * 2) / row_bytes);
  long Rc = 128;
  while (Rc * 2 <= maxRc && Rc < 8192) Rc <<= 1;
  size_t P = (size_t)Rc * HID;
  unsigned short* bufA = wsp + wtotal;
  unsigned short* bufB = bufA + 10 * P;
  float* fbuf = (float*)(bufB + 10 * P);

  wsplit<<<HID, HID, 0, stream>>>(W1, Wt + 0 * WT1, Wt + 1 * WT1);
  wsplit<<<HID, HID, 0, stream>>>(W2, Wt + 2 * WT1, Wt + 3 * WT1);
  wsplit<<<HID, HID, 0, stream>>>(W3, Wt + 4 * WT1, Wt + 5 * WT1);

  const float sc_f = 0.5f / (float)N_INT;
  const float sc_i = 0.5f / (float)N_INIT;

  // ---- interior pass (5 streams) ----
  for (long i0 = 0; i0 < N_INT; i0 += Rc) {
    long rem = N_INT - i0;
    int rows = (int)(rem < Rc ? rem : Rc);
    layer0_int<<<rows, HID, 0, stream>>>(xt_int, i0, rows, W0, b0, bufA, P);
    int nwg = (rows / 32) * 4;
    gemm_mfma<5, false><<<nwg, 256, 0, stream>>>(bufA, Wt + 0 * WT1, Wt + 1 * WT1, b1, bufB, nullptr, P, nwg);
    gemm_mfma<5, false><<<nwg, 256, 0, stream>>>(bufB, Wt + 2 * WT1, Wt + 3 * WT1, b2, bufA, nullptr, P, nwg);
    gemm_mfma<5, true><<<nwg, 256, 0, stream>>>(bufA, Wt + 4 * WT1, Wt + 5 * WT1, b3, nullptr, fbuf, P, nwg);
    final_int<<<(rows + 3) / 4, 256, 0, stream>>>(fbuf, P, W4, f + i0, c, out, rows, sc_f);
  }

  // ---- init pass (2 streams) ----
  for (long i0 = 0; i0 < N_INIT; i0 += Rc) {
    long rem = N_INIT - i0;
    int rows = (int)(rem < Rc ? rem : Rc);
    layer0_init<<<rows, HID, 0, stream>>>(xt_init, i0, rows, W0, b0, bufA, P);
    int nwg = (rows / 32) * 4;
    gemm_mfma<2, false><<<nwg, 256, 0, stream>>>(bufA, Wt + 0 * WT1, Wt + 1 * WT1, b1, bufB, nullptr, P, nwg);
    gemm_mfma<2, false><<<nwg, 256, 0, stream>>>(bufB, Wt + 2 * WT1, Wt + 3 * WT1, b2, bufA, nullptr, P, nwg);
    gemm_mfma<2, true><<<nwg, 256, 0, stream>>>(bufA, Wt + 4 * WT1, Wt + 5 * WT1, b3, nullptr, fbuf, P, nwg);
    final_init<<<(rows + 3) / 4, 256, 0, stream>>>(fbuf, P, W4, b4, g + i0, gd + i0, out, rows, sc_i);
  }
}